// Round 4
// baseline (427.386 us; speedup 1.0000x reference)
//
#include <hip/hip_runtime.h>
#include <cstdint>

#define N_ 32
#define H_ 56
#define W_ 56
#define C_ 256
#define HP 58
#define WP 58

// ws layout (bytes)
#define OFF_KB     0          // u64[256][9][4]   = 73728   [co][tap][word]
#define OFF_PAL    73728      // f32[36][256]     = 36864
#define OFF_ALF    110592     // f32[256]         = 1024
#define OFF_XB     114688     // u64[32*58*58][4] = 3444736 [padded pix][word]
#define OFF_BETA   3559424    // f32[32*58*58]    = 430592  (adjacent to XB)

// Channel map (both packers): channel c = 4*b + j -> word j, bit b.
// Popcount dot is permutation-invariant; alpha/beta are plain sums.

// ---------------- kernel 1: pack weight sign bits + |k| partials ------------
// grid = 36 (p = tap, j = word), block = 1024 = (q in [0,4)) x (co in [0,256)).
// Thread (q,co) covers b in [16q, 16q+16): 16 independent coalesced loads
// (round-3 pack_w serialized 64 loads/thread at 16% occupancy).
__global__ __launch_bounds__(1024) void pack_w(const float* __restrict__ k,
                                               uint64_t* __restrict__ kb,
                                               float* __restrict__ palpha) {
    int p = blockIdx.x >> 2, j = blockIdx.x & 3;
    int q = threadIdx.x >> 8;
    int co = threadIdx.x & 255;
    uint64_t bits = 0; float s = 0.f;
    #pragma unroll
    for (int i = 0; i < 16; ++i) {
        int b = q * 16 + i;
        float v = k[(p * 256 + 4 * b + j) * 256 + co];
        bits |= (uint64_t)(v > 0.f) << b;
        s += fabsf(v);
    }
    __shared__ uint64_t pb[4][256];
    __shared__ float ps[4][256];
    pb[q][co] = bits; ps[q][co] = s;
    __syncthreads();
    if (q == 0) {
        uint64_t w = pb[0][co] | pb[1][co] | pb[2][co] | pb[3][co];
        float t = ps[0][co] + ps[1][co] + ps[2][co] + ps[3][co];
        kb[((size_t)co * 9 + p) * 4 + j] = w;           // [co][tap][word]
        palpha[(p * 4 + j) * 256 + co] = t;
    }
}

// ---------------- kernel 1b: alpha = mean|k| per cout -----------------------
__global__ __launch_bounds__(256) void alpha_k(const float* __restrict__ palpha,
                                               float* __restrict__ alphaF) {
    int co = threadIdx.x;
    float s = 0.f;
    #pragma unroll
    for (int i = 0; i < 36; ++i) s += palpha[i * 256 + co];
    alphaF[co] = s * (1.f / 2304.f);
}

// ---------------- kernel 2: pack input sign bits + beta ---------------------
// One wave per interior pixel, no loops: lane loads float4 (channels 4L..4L+3),
// 4 ballots build the 4 words, shfl-reduce |x| for beta. Borders were zeroed
// by memset (sign(0) = -1 -> bit 0; beta contribution 0). Grid 25088, pure
// streaming reads (4 KB contiguous per block).
__global__ __launch_bounds__(256) void pack_x(const float4* __restrict__ x4,
                                              uint64_t* __restrict__ xb,
                                              float* __restrict__ beta) {
    int wave = threadIdx.x >> 6, lane = threadIdx.x & 63;
    int P = blockIdx.x * 4 + wave;           // interior pixel, < 100352
    float4 v = x4[(size_t)P * 64 + lane];
    uint64_t m0 = __ballot(v.x > 0.f);
    uint64_t m1 = __ballot(v.y > 0.f);
    uint64_t m2 = __ballot(v.z > 0.f);
    uint64_t m3 = __ballot(v.w > 0.f);
    float s = fabsf(v.x) + fabsf(v.y) + fabsf(v.z) + fabsf(v.w);
    #pragma unroll
    for (int m = 32; m >= 1; m >>= 1) s += __shfl_xor(s, m, 64);
    int n = P / (H_ * W_);
    int r = P % (H_ * W_);
    int hy = r / W_, wx = r % W_;
    size_t pp = ((size_t)n * HP + hy + 1) * WP + (wx + 1);
    if (lane < 4) {
        uint64_t mw = (lane == 0) ? m0 : (lane == 1) ? m1 : (lane == 2) ? m2 : m3;
        xb[pp * 4 + lane] = mw;
    }
    if (lane == 0) beta[pp] = s * (1.f / 256.f);
}

// ---------------- kernel 3: binary conv, lane = column, SGPR weights --------
// grid = N_*H_ (output row), block = 256 = 4 independent waves, wave = 64-cout
// quarter. Lane c holds padded column c's 12 x-words in registers (one L2 read
// per row — no LDS broadcast). co-loop is wave-uniform -> kr[36] arrives via
// s_load into SGPRs (no VGPR pressure -> no AGPR shuffling). T[kw] partials
// combine across lanes with 2 shfl_down. Results staged per-wave in a
// stride-17 LDS tile, stored coalesced (4x64B segments per instr).
__global__ __launch_bounds__(256) void bconv(
        const uint64_t* __restrict__ xb, const float* __restrict__ beta,
        const uint64_t* __restrict__ kb, const float* __restrict__ alphaF,
        const float* __restrict__ bias, float* __restrict__ out) {
    int bx = blockIdx.x;                     // n*H_ + h
    int n = bx / H_, h = bx % H_;
    int wave = threadIdx.x >> 6, lane = threadIdx.x & 63;
    int co0 = wave * 64;
    int c = lane < 57 ? lane : 57;           // padded column, clamp tail lanes

    // 12 x-words for this column (3 padded rows x 4 words) -> 24 VGPRs
    uint64_t xw[3][4];
    #pragma unroll
    for (int r = 0; r < 3; ++r) {
        const ulonglong2* p2 =
            (const ulonglong2*)(xb + ((size_t)(n * HP + h + r) * WP + c) * 4);
        ulonglong2 a = p2[0], b = p2[1];
        xw[r][0] = a.x; xw[r][1] = a.y; xw[r][2] = b.x; xw[r][3] = b.y;
    }

    // bS = 3x3 avg-pool of beta at output column `lane`
    float bSw = 0.f;
    if (lane < W_) {
        #pragma unroll
        for (int r = 0; r < 3; ++r)
            #pragma unroll
            for (int d = 0; d < 3; ++d)
                bSw += beta[(size_t)(n * HP + h + r) * WP + lane + d];
        bSw *= (1.f / 9.f);
    }

    __shared__ float ts[4][W_ * 17];         // per-wave transpose tile
    float* t = ts[wave];
    float* orow = out + (size_t)bx * W_ * C_;

    for (int ci = 0; ci < 64; ++ci) {
        int co = co0 + ci;                   // wave-uniform
        const uint64_t* kr = kb + (size_t)co * 36;   // -> s_load_dwordx16
        uint32_t T0 = 0, T1 = 0, T2 = 0;
        #pragma unroll
        for (int r = 0; r < 3; ++r) {
            #pragma unroll
            for (int j = 0; j < 4; ++j) {
                uint64_t xv = xw[r][j];
                T0 += __popcll(xv ^ kr[(r * 3 + 0) * 4 + j]);
                T1 += __popcll(xv ^ kr[(r * 3 + 1) * 4 + j]);
                T2 += __popcll(xv ^ kr[(r * 3 + 2) * 4 + j]);
            }
        }
        // output w gets taps kw=0,1,2 from padded columns w, w+1, w+2
        uint32_t tot = T0 + __shfl_down(T1, 1) + __shfl_down(T2, 2);
        float conv = (float)(2304 - 2 * (int)tot);
        float res = conv * bSw * alphaF[co] + bias[co];
        if (lane < W_) t[lane * 17 + (ci & 15)] = res;
        if ((ci & 15) == 15) {               // flush 56x16 co-tile, coalesced
            int cb = co0 + (ci & ~15);
            #pragma unroll
            for (int i = 0; i < 14; ++i) {
                int idx = i * 64 + lane;     // < 896 = 56*16
                int w = idx >> 4, cc = idx & 15;
                orow[(size_t)w * C_ + cb + cc] = t[w * 17 + cc];
            }
        }
    }
}

extern "C" void kernel_launch(void* const* d_in, const int* in_sizes, int n_in,
                              void* d_out, int out_size, void* d_ws, size_t ws_size,
                              hipStream_t stream) {
    const float* x    = (const float*)d_in[0];
    const float* k    = (const float*)d_in[1];
    const float* bias = (const float*)d_in[2];
    float* out = (float*)d_out;

    char* ws = (char*)d_ws;
    uint64_t* kb     = (uint64_t*)(ws + OFF_KB);
    float*    palpha = (float*)(ws + OFF_PAL);
    float*    alphaF = (float*)(ws + OFF_ALF);
    uint64_t* xb     = (uint64_t*)(ws + OFF_XB);
    float*    beta   = (float*)(ws + OFF_BETA);

    // zero padded borders of xb + beta (harness poisons ws every call)
    hipMemsetAsync(ws + OFF_XB, 0, 3444736 + 430592, stream);

    pack_w<<<36, 1024, 0, stream>>>(k, kb, palpha);
    alpha_k<<<1, 256, 0, stream>>>(palpha, alphaF);
    pack_x<<<(N_ * H_ * W_) / 4, 256, 0, stream>>>((const float4*)x, xb, beta);
    bconv<<<N_ * H_, 256, 0, stream>>>(xb, beta, kb, alphaF, bias, out);
}

// Round 5
// 355.839 us; speedup vs baseline: 1.2011x; 1.2011x over previous
//
#include <hip/hip_runtime.h>
#include <cstdint>

#define N_ 32
#define H_ 56
#define W_ 56
#define C_ 256
#define HP 58
#define WP 58

// ws layout (bytes)
#define OFF_KB     0          // u64[256][9][4]   = 73728   [co][tap][word]
#define OFF_PAL    73728      // f32[36][256]     = 36864
#define OFF_ALF    110592     // f32[256]         = 1024
#define OFF_XB     114688     // u64[32*58*58][4] = 3444736 [padded pix][word]
#define OFF_BETA   3559424    // f32[32*58*58]    = 430592  (adjacent to XB)

// Channel map (both packers): channel c = 4*b + j -> word j, bit b.
// Popcount dot is permutation-invariant; alpha/beta are plain sums.

// ---------------- kernel 1: pack weight sign bits + |k| partials ------------
__global__ __launch_bounds__(1024) void pack_w(const float* __restrict__ k,
                                               uint64_t* __restrict__ kb,
                                               float* __restrict__ palpha) {
    int p = blockIdx.x >> 2, j = blockIdx.x & 3;
    int q = threadIdx.x >> 8;
    int co = threadIdx.x & 255;
    uint64_t bits = 0; float s = 0.f;
    #pragma unroll
    for (int i = 0; i < 16; ++i) {
        int b = q * 16 + i;
        float v = k[(p * 256 + 4 * b + j) * 256 + co];
        bits |= (uint64_t)(v > 0.f) << b;
        s += fabsf(v);
    }
    __shared__ uint64_t pb[4][256];
    __shared__ float ps[4][256];
    pb[q][co] = bits; ps[q][co] = s;
    __syncthreads();
    if (q == 0) {
        uint64_t w = pb[0][co] | pb[1][co] | pb[2][co] | pb[3][co];
        float t = ps[0][co] + ps[1][co] + ps[2][co] + ps[3][co];
        kb[((size_t)co * 9 + p) * 4 + j] = w;           // [co][tap][word]
        palpha[(p * 4 + j) * 256 + co] = t;
    }
}

// ---------------- kernel 1b: alpha = mean|k| per cout -----------------------
__global__ __launch_bounds__(256) void alpha_k(const float* __restrict__ palpha,
                                               float* __restrict__ alphaF) {
    int co = threadIdx.x;
    float s = 0.f;
    #pragma unroll
    for (int i = 0; i < 36; ++i) s += palpha[i * 256 + co];
    alphaF[co] = s * (1.f / 2304.f);
}

// ---------------- kernel 2: pack input sign bits + beta ---------------------
// One wave per interior pixel: lane loads float4 (channels 4L..4L+3), 4 ballots
// build the 4 words, shfl-reduce |x| for beta. Borders zeroed by memset.
__global__ __launch_bounds__(256) void pack_x(const float4* __restrict__ x4,
                                              uint64_t* __restrict__ xb,
                                              float* __restrict__ beta) {
    int wave = threadIdx.x >> 6, lane = threadIdx.x & 63;
    int P = blockIdx.x * 4 + wave;           // interior pixel, < 100352
    float4 v = x4[(size_t)P * 64 + lane];
    uint64_t m0 = __ballot(v.x > 0.f);
    uint64_t m1 = __ballot(v.y > 0.f);
    uint64_t m2 = __ballot(v.z > 0.f);
    uint64_t m3 = __ballot(v.w > 0.f);
    float s = fabsf(v.x) + fabsf(v.y) + fabsf(v.z) + fabsf(v.w);
    #pragma unroll
    for (int m = 32; m >= 1; m >>= 1) s += __shfl_xor(s, m, 64);
    int n = P / (H_ * W_);
    int r = P % (H_ * W_);
    int hy = r / W_, wx = r % W_;
    size_t pp = ((size_t)n * HP + hy + 1) * WP + (wx + 1);
    if (lane < 4) {
        uint64_t mw = (lane == 0) ? m0 : (lane == 1) ? m1 : (lane == 2) ? m2 : m3;
        xb[pp * 4 + lane] = mw;
    }
    if (lane == 0) beta[pp] = s * (1.f / 256.f);
}

// ---------------- kernel 3: binary conv, lane = column ----------------------
// grid = (448, 2): blockIdx.x = n*14 + hq (4 output rows h0=4*hq), blockIdx.y
// = co-half. Block = 4 waves; wave -> 32-cout window. Lane c holds column c's
// 24 x-words (6 padded rows) in VGPRs. Weights for the block's 128 couts live
// in LDS; the ci-loop reads them with WAVE-UNIFORM ds_read_b128 (broadcast,
// conflict-free) — no per-lane VMEM (R4 failure), no per-thread weight arrays
// (R1-R3 AGPR-shuffle failure). Tap partials T<=768 packed as u16 pairs ->
// 4 ds_bpermutes/ci. Results staged in a per-wave tile with lane-contiguous
// float4 writes, flushed every 8 ci as 32B-segment coalesced stores.
__global__ __launch_bounds__(256, 2) void bconv(
        const uint64_t* __restrict__ xb, const float* __restrict__ beta,
        const uint64_t* __restrict__ kb, const float* __restrict__ alphaF,
        const float* __restrict__ bias, float* __restrict__ out) {
    int nb = blockIdx.x;                 // n*14 + hq
    int n = nb / 14, hq = nb % 14;
    int h0 = hq * 4;                     // output rows h0..h0+3
    int cog = blockIdx.y << 7;           // co half-base
    int tid = threadIdx.x, wave = tid >> 6, lane = tid & 63;

    __shared__ __align__(16) uint64_t ks[128 * 36];     // 36864 B
    __shared__ __align__(16) float ts[4][8 * 228];      // 29184 B (4 waves)

    // stage this block's 128 couts of packed weights (kb layout matches)
    {
        const ulonglong2* ksrc = (const ulonglong2*)(kb + (size_t)cog * 36);
        ulonglong2* kdst = (ulonglong2*)ks;
        for (int i = tid; i < 128 * 18; i += 256) kdst[i] = ksrc[i];
    }

    // 24 x-words for this padded column (6 rows x 4 words) -> 48 VGPRs
    int c = lane < 58 ? lane : 57;
    uint64_t xw[6][4];
    #pragma unroll
    for (int r = 0; r < 6; ++r) {
        const ulonglong2* p2 =
            (const ulonglong2*)(xb + ((size_t)(n * HP + h0 + r) * WP + c) * 4);
        ulonglong2 a = p2[0], b = p2[1];
        xw[r][0] = a.x; xw[r][1] = a.y; xw[r][2] = b.x; xw[r][3] = b.y;
    }

    // bS[rr] = 3x3 avg-pool of beta at output (h0+rr, lane)
    float bS[4];
    {
        float rs[6];
        #pragma unroll
        for (int r = 0; r < 6; ++r) {
            const float* bp = beta + (size_t)(n * HP + h0 + r) * WP
                            + (lane < W_ ? lane : 0);
            rs[r] = bp[0] + bp[1] + bp[2];
        }
        #pragma unroll
        for (int rr = 0; rr < 4; ++rr)
            bS[rr] = (rs[rr] + rs[rr + 1] + rs[rr + 2]) * (1.f / 9.f);
    }

    // bpermute byte-addresses for pull-from lane+1 / lane+2 (hoisted)
    int a1 = (lane + 1 < 64 ? lane + 1 : 63) << 2;
    int a2 = (lane + 2 < 64 ? lane + 2 : 63) << 2;

    __syncthreads();

    float* tw = ts[wave];
    int cow = cog + wave * 32;           // wave's co window [cow, cow+32)
    const ulonglong2* kwv = (const ulonglong2*)ks + (size_t)(wave * 32) * 18;

    #pragma unroll 1
    for (int ci = 0; ci < 32; ++ci) {
        int co = cow + ci;
        const ulonglong2* kp = kwv + ci * 18;   // wave-uniform LDS address
        uint32_t T[3][4] = {};               // [kw][rr], each <= 768
        #pragma unroll
        for (int t9 = 0; t9 < 9; ++t9) {     // tap = (r=t9/3, kw=t9%3)
            #pragma unroll
            for (int jp = 0; jp < 2; ++jp) {
                ulonglong2 kk = kp[t9 * 2 + jp];     // ds_read_b128 broadcast
                int r = t9 / 3, kw = t9 % 3;
                #pragma unroll
                for (int rr = 0; rr < 4; ++rr) {
                    T[kw][rr] += __popcll(xw[rr + r][jp * 2]     ^ kk.x)
                               + __popcll(xw[rr + r][jp * 2 + 1] ^ kk.y);
                }
            }
        }
        // pack u16 pairs (sums < 65536: no carry), combine taps across lanes
        uint32_t t0a = T[0][0] | (T[0][1] << 16), t0b = T[0][2] | (T[0][3] << 16);
        uint32_t t1a = T[1][0] | (T[1][1] << 16), t1b = T[1][2] | (T[1][3] << 16);
        uint32_t t2a = T[2][0] | (T[2][1] << 16), t2b = T[2][2] | (T[2][3] << 16);
        uint32_t sa = t0a + (uint32_t)__builtin_amdgcn_ds_bpermute(a1, (int)t1a)
                          + (uint32_t)__builtin_amdgcn_ds_bpermute(a2, (int)t2a);
        uint32_t sb = t0b + (uint32_t)__builtin_amdgcn_ds_bpermute(a1, (int)t1b)
                          + (uint32_t)__builtin_amdgcn_ds_bpermute(a2, (int)t2b);
        float al = alphaF[co];
        float bv = bias[co];
        float r0 = (2304.f - 2.f * (float)(sa & 0xffff)) * (bS[0] * al) + bv;
        float r1 = (2304.f - 2.f * (float)(sa >> 16))    * (bS[1] * al) + bv;
        float r2 = (2304.f - 2.f * (float)(sb & 0xffff)) * (bS[2] * al) + bv;
        float r3 = (2304.f - 2.f * (float)(sb >> 16))    * (bS[3] * al) + bv;
        if (lane < W_) {                 // tile write: lane-contiguous 16 B
            float4 v4 = make_float4(r0, r1, r2, r3);
            *(float4*)&tw[(ci & 7) * 228 + lane * 4] = v4;
        }
        if ((ci & 7) == 7) {             // flush 8 co x 4 rows x 56 w
            int f = ci >> 3;
            #pragma unroll
            for (int i = 0; i < 28; ++i) {
                int idx = i * 64 + lane;
                int cc = idx & 7, rr = (idx >> 3) & 3, w = idx >> 5;
                out[((size_t)((n * H_) + h0 + rr) * W_ + w) * C_
                    + cow + f * 8 + cc] = tw[cc * 228 + w * 4 + rr];
            }
        }
    }
}

extern "C" void kernel_launch(void* const* d_in, const int* in_sizes, int n_in,
                              void* d_out, int out_size, void* d_ws, size_t ws_size,
                              hipStream_t stream) {
    const float* x    = (const float*)d_in[0];
    const float* k    = (const float*)d_in[1];
    const float* bias = (const float*)d_in[2];
    float* out = (float*)d_out;

    char* ws = (char*)d_ws;
    uint64_t* kb     = (uint64_t*)(ws + OFF_KB);
    float*    palpha = (float*)(ws + OFF_PAL);
    float*    alphaF = (float*)(ws + OFF_ALF);
    uint64_t* xb     = (uint64_t*)(ws + OFF_XB);
    float*    beta   = (float*)(ws + OFF_BETA);

    // zero padded borders of xb + beta (harness poisons ws every call)
    hipMemsetAsync(ws + OFF_XB, 0, 3444736 + 430592, stream);

    pack_w<<<36, 1024, 0, stream>>>(k, kb, palpha);
    alpha_k<<<1, 256, 0, stream>>>(palpha, alphaF);
    pack_x<<<(N_ * H_ * W_) / 4, 256, 0, stream>>>((const float4*)x, xb, beta);
    bconv<<<dim3(14 * N_, 2), 256, 0, stream>>>(xb, beta, kb, alphaF, bias, out);
}